// Round 3
// baseline (242.243 us; speedup 1.0000x reference)
//
#include <hip/hip_runtime.h>

#define SEG 256
#define SMOOTH_K 9
#define BASE_AMP 0.08f
#define L 4096
#define ROW (2 * L)          // floats per batch row (8192)

// ---------------------------------------------------------------------------
// Kernel 1: effective pattern -> d_ws (512 floats: [2][256])
// ---------------------------------------------------------------------------
__global__ __launch_bounds__(256) void pattern_kernel(
    const float* __restrict__ pi, const float* __restrict__ pq,
    float* __restrict__ pat_out) {
    __shared__ float wsum0[4], wsum1[4], wsq[4];

    const int i = threadIdx.x;            // 0..255 (position)
    // 'same' box smooth, zero padding, always /9 (count_include_pad=True)
    float v0 = 0.f, v1 = 0.f;
    #pragma unroll
    for (int j = -(SMOOTH_K / 2); j <= SMOOTH_K / 2; ++j) {
        int k = i + j;
        if (k >= 0 && k < SEG) { v0 += pi[k]; v1 += pq[k]; }
    }
    v0 *= (1.0f / SMOOTH_K);
    v1 *= (1.0f / SMOOTH_K);

    float s0 = v0, s1 = v1;
    #pragma unroll
    for (int off = 32; off; off >>= 1) {
        s0 += __shfl_down(s0, off);
        s1 += __shfl_down(s1, off);
    }
    const int wid = i >> 6, lane = i & 63;
    if (lane == 0) { wsum0[wid] = s0; wsum1[wid] = s1; }
    __syncthreads();
    const float m0 = (wsum0[0] + wsum0[1] + wsum0[2] + wsum0[3]) * (1.0f / SEG);
    const float m1 = (wsum1[0] + wsum1[1] + wsum1[2] + wsum1[3]) * (1.0f / SEG);
    const float d0 = v0 - m0;
    const float d1 = v1 - m1;

    float q = d0 * d0 + d1 * d1;
    #pragma unroll
    for (int off = 32; off; off >>= 1) q += __shfl_down(q, off);
    if (lane == 0) wsq[wid] = q;
    __syncthreads();
    const float msq = (wsq[0] + wsq[1] + wsq[2] + wsq[3]) * (1.0f / (2 * SEG));
    const float scale = BASE_AMP / sqrtf(msq + 1e-8f);

    pat_out[i]       = d0 * scale;
    pat_out[SEG + i] = d1 * scale;
}

// ---------------------------------------------------------------------------
// Kernel 2: one block per row. Stream the row: every float4 NOT overlapping
// the segment is stored immediately (no dependency on the reduction). The
// <=130 float4 overlapping [s, s+256) are stashed in LDS and patched with
// amp*pat after the block reduce.
// ---------------------------------------------------------------------------
__global__ __launch_bounds__(256) void apply_kernel(
    const float* __restrict__ x, const int* __restrict__ starts,
    const float* __restrict__ pat, float* __restrict__ out) {
    const int b = blockIdx.x;
    const int t = threadIdx.x;

    const float4* __restrict__ xr =
        reinterpret_cast<const float4*>(x + (size_t)b * ROW);
    float4* __restrict__ outr = reinterpret_cast<float4*>(out + (size_t)b * ROW);

    __shared__ float  spat[2 * SEG];
    __shared__ float4 stash[2 * 66];   // per-channel contiguous slice, <=65 each
    __shared__ float  wred[4];

    spat[t]       = pat[t];
    spat[t + SEG] = pat[t + SEG];

    const int s    = starts[b];
    const int s4   = s >> 2;                 // first overlapping float4 (per ch)
    const int e4   = (s + SEG - 1) >> 2;     // last overlapping float4 (per ch)
    const int nper = e4 - s4 + 1;            // 64 or 65

    float ssq = 0.f;
    #pragma unroll
    for (int k = 0; k < 8; ++k) {
        const int idx = t + k * 256;         // float4 index within row
        float4 v = xr[idx];
        ssq += v.x * v.x + v.y * v.y + v.z * v.z + v.w * v.w;
        const int c  = idx >> 10;            // channel
        const int l4 = idx & 1023;           // float4 index within channel
        if (l4 >= s4 && l4 <= e4) {
            stash[c * 66 + (l4 - s4)] = v;   // defer until amp is known
        } else {
            outr[idx] = v;                   // independent of reduction: flows
        }
    }

    // block reduce sum-of-squares
    #pragma unroll
    for (int off = 32; off; off >>= 1) ssq += __shfl_down(ssq, off);
    if ((t & 63) == 0) wred[t >> 6] = ssq;
    __syncthreads();   // covers stash, spat, wred
    const float amp =
        sqrtf((wred[0] + wred[1] + wred[2] + wred[3]) * (1.0f / ROW) + 1e-12f);

    // tail: patch the stashed float4s (2*nper <= 130 threads active)
    if (t < 2 * nper) {
        const int c  = (t >= nper) ? 1 : 0;
        const int j  = t - c * nper;
        const int l4 = s4 + j;
        float4 v = stash[c * 66 + j];
        const float* __restrict__ pc = spat + c * SEG;
        const int r = (l4 << 2) - s;         // in [-3, 255]
        if (r >= 0     && r < SEG)     v.x += amp * pc[r];
        if (r + 1 >= 0 && r + 1 < SEG) v.y += amp * pc[r + 1];
        if (r + 2 >= 0 && r + 2 < SEG) v.z += amp * pc[r + 2];
        if (r + 3 >= 0 && r + 3 < SEG) v.w += amp * pc[r + 3];
        outr[(c << 10) + l4] = v;
    }
}

// ---------------------------------------------------------------------------
extern "C" void kernel_launch(void* const* d_in, const int* in_sizes, int n_in,
                              void* d_out, int out_size, void* d_ws,
                              size_t ws_size, hipStream_t stream) {
    const float* x      = (const float*)d_in[0];
    const float* pi     = (const float*)d_in[1];
    const float* pq     = (const float*)d_in[2];
    const int*   starts = (const int*)d_in[3];
    float* out = (float*)d_out;
    float* pat = (float*)d_ws;   // 512 floats

    const int B = in_sizes[0] / ROW;   // 4096

    pattern_kernel<<<1, 256, 0, stream>>>(pi, pq, pat);
    apply_kernel<<<B, 256, 0, stream>>>(x, starts, pat, out);
}